// Round 16
// baseline (679.216 us; speedup 1.0000x reference)
//
#include <hip/hip_runtime.h>
#include <hip/hip_bf16.h>

#define B_ 1024
#define L_ 256
#define D_ 256
#define H_ 512
#define U_ 512
#define M_ (B_ * L_)

#define BM 128
#define BN 128
#define BK 64
#define REP 4   // diagnostic loop multiplier

typedef float f32x4 __attribute__((ext_vector_type(4)));
typedef short bf16x8 __attribute__((ext_vector_type(8)));

__device__ __forceinline__ short f2bf(float f) {
  unsigned u = __float_as_uint(f);
  u += 0x7fffu + ((u >> 16) & 1u);
  return (short)(u >> 16);
}

__device__ __forceinline__ void load16_g2l(const void* g, void* l) {
  __builtin_amdgcn_global_load_lds(
      (const __attribute__((address_space(1))) unsigned int*)g,
      (__attribute__((address_space(3))) unsigned int*)l, 16, 0, 0);
}

__device__ __forceinline__ float fast_tanh(float x) {
  float e = __expf(2.0f * x);
  return 1.0f - 2.0f * __builtin_amdgcn_rcpf(e + 1.0f);
}

// ---------------- prep: W1 [D,U] fp32 -> W1T [U,D] bf16 ----------------
__global__ void k_w1t(const float* __restrict__ W1, short* __restrict__ W1T) {
  int idx = blockIdx.x * 256 + threadIdx.x;
  int u = idx >> 8;
  int d = idx & 255;
  W1T[idx] = f2bf(W1[(size_t)d * U_ + u]);
}

// ---------------- projh ----------------
__global__ void k_projh(const float* __restrict__ hidden, const float* __restrict__ W2,
                        const float* __restrict__ b1, const float* __restrict__ b2,
                        float* __restrict__ ph) {
  int u = blockIdx.x * 256 + threadIdx.x;
  int b0 = blockIdx.y * 8;
  float acc[8] = {0.f, 0.f, 0.f, 0.f, 0.f, 0.f, 0.f, 0.f};
  for (int h = 0; h < H_; ++h) {
    float w = W2[(size_t)h * U_ + u];
#pragma unroll
    for (int i = 0; i < 8; ++i) acc[i] = fmaf(hidden[(size_t)(b0 + i) * H_ + h], w, acc[i]);
  }
  float bias = b1[u] + b2[u];
#pragma unroll
  for (int i = 0; i < 8; ++i) ph[(size_t)(b0 + i) * U_ + u] = acc[i] + bias;
}

// ---------------- main: R7 verbatim (best measured: 184 us) ----------------
__global__ __launch_bounds__(256, 3) void k_gemm(
    const float* __restrict__ F, const short* __restrict__ W1T,
    const float* __restrict__ ph, const float* __restrict__ Wv,
    float* __restrict__ logits) {
  __shared__ __align__(16) short As[BM * BK];
  __shared__ __align__(16) short Bs[2][BN * BK];

  const int tid = threadIdx.x;
  const int lane = tid & 63;
  const int hi = lane >> 4;
  const int wid = tid >> 6;
  const int wr = wid >> 1, wc = wid & 1;
  const int tile = ((blockIdx.x & 7) << 10) | (blockIdx.x >> 3);
  const int ntile = tile & 3;
  const int mtile = tile >> 2;
  const int m0 = mtile * BM;
  const int n0 = ntile * BN;
  const int b = m0 >> 8;

  const bf16x8* As8 = (const bf16x8*)As;

  const float* agp[4];
  int aslot[4];
  const short* bgp[4];
#pragma unroll
  for (int i = 0; i < 4; ++i) {
    int s = i * 256 + tid;
    int arow = s >> 3;
    int akq = (s & 7) ^ (arow & 7);
    agp[i] = F + (size_t)(m0 + arow) * D_ + akq * 8;
    aslot[i] = s;
    bgp[i] = W1T + (size_t)(n0 + arow) * D_ + akq * 8;
  }

  f32x4 acc[4][4];
  const f32x4 fz = {0.f, 0.f, 0.f, 0.f};
#pragma unroll
  for (int mi = 0; mi < 4; ++mi)
#pragma unroll
    for (int ni = 0; ni < 4; ++ni) acc[mi][ni] = fz;

  f32x4 ar[4][2];
#pragma unroll
  for (int i = 0; i < 4; ++i) {
    ar[i][0] = *(const f32x4*)(agp[i]);
    ar[i][1] = *(const f32x4*)(agp[i] + 4);
    agp[i] += BK;
  }
#pragma unroll
  for (int i = 0; i < 4; ++i) {
    load16_g2l(bgp[i], &Bs[0][(size_t)(i * 256 + tid) * 8]);
    bgp[i] += BK;
  }

  for (int kt = 0; kt < 4; ++kt) {
    const bf16x8* BsC = (const bf16x8*)Bs[kt & 1];
    __syncthreads();
#pragma unroll
    for (int i = 0; i < 4; ++i) {
      bf16x8 w;
#pragma unroll
      for (int j = 0; j < 4; ++j) { w[j] = f2bf(ar[i][0][j]); w[4 + j] = f2bf(ar[i][1][j]); }
      ((bf16x8*)As)[aslot[i]] = w;
    }
    __syncthreads();
    if (kt < 3) {
#pragma unroll
      for (int i = 0; i < 4; ++i) {
        ar[i][0] = *(const f32x4*)(agp[i]);
        ar[i][1] = *(const f32x4*)(agp[i] + 4);
        agp[i] += BK;
      }
#pragma unroll
      for (int i = 0; i < 4; ++i) {
        load16_g2l(bgp[i], &Bs[(kt + 1) & 1][(size_t)(i * 256 + tid) * 8]);
        bgp[i] += BK;
      }
    }
#pragma unroll
    for (int kk = 0; kk < 2; ++kk) {
      bf16x8 af[4], bfr[4];
#pragma unroll
      for (int mi = 0; mi < 4; ++mi) {
        int rA = wr * 64 + mi * 16 + (lane & 15);
        af[mi] = As8[rA * 8 + ((kk * 4 + hi) ^ (rA & 7))];
      }
#pragma unroll
      for (int ni = 0; ni < 4; ++ni) {
        int nB = wc * 64 + ni * 16 + (lane & 15);
        bfr[ni] = BsC[nB * 8 + ((kk * 4 + hi) ^ (nB & 7))];
      }
#pragma unroll
      for (int mi = 0; mi < 4; ++mi)
#pragma unroll
        for (int ni = 0; ni < 4; ++ni)
          acc[mi][ni] = __builtin_amdgcn_mfma_f32_16x16x32_bf16(af[mi], bfr[ni], acc[mi][ni], 0, 0, 0);
    }
  }

  const float* phr = ph + (size_t)b * U_;
  float phv[4], wvv[4];
#pragma unroll
  for (int ni = 0; ni < 4; ++ni) {
    int u = n0 + wc * 64 + ni * 16 + (lane & 15);
    phv[ni] = phr[u];
    wvv[ni] = Wv[u];
  }
#pragma unroll
  for (int mi = 0; mi < 4; ++mi) {
    float cs[4] = {0.f, 0.f, 0.f, 0.f};
#pragma unroll
    for (int ni = 0; ni < 4; ++ni) {
#pragma unroll
      for (int r = 0; r < 4; ++r) {
        float x = acc[mi][ni][r] + phv[ni];
        cs[r] += fast_tanh(x) * wvv[ni];
      }
    }
#pragma unroll
    for (int off = 1; off < 16; off <<= 1) {
#pragma unroll
      for (int r = 0; r < 4; ++r) cs[r] += __shfl_xor(cs[r], off);
    }
    if ((lane & 15) == 0) {
      int g = m0 + wr * 64 + mi * 16 + ((lane >> 4) << 2);
#pragma unroll
      for (int r = 0; r < 4; ++r) atomicAdd(&logits[g + r], cs[r]);
    }
  }
}

// ---------------- DIAG 1: staging+barriers only, REP x (no ds_read/MFMA/epilogue) ----------------
__global__ __launch_bounds__(256, 3) void k_diag_stage(
    const float* __restrict__ F, const short* __restrict__ W1T, float* __restrict__ dummy) {
  __shared__ __align__(16) short As[BM * BK];
  __shared__ __align__(16) short Bs[2][BN * BK];
  const int tid = threadIdx.x;
  const int tile = ((blockIdx.x & 7) << 10) | (blockIdx.x >> 3);
  const int ntile = tile & 3;
  const int mtile = tile >> 2;
  const int m0 = mtile * BM;
  const int n0 = ntile * BN;

  const float* agp0[4];
  int aslot[4];
  const short* bgp0[4];
#pragma unroll
  for (int i = 0; i < 4; ++i) {
    int s = i * 256 + tid;
    int arow = s >> 3;
    int akq = (s & 7) ^ (arow & 7);
    agp0[i] = F + (size_t)(m0 + arow) * D_ + akq * 8;
    aslot[i] = s;
    bgp0[i] = W1T + (size_t)(n0 + arow) * D_ + akq * 8;
  }

  for (int rep = 0; rep < REP; ++rep) {
    const float* agp[4];
    const short* bgp[4];
#pragma unroll
    for (int i = 0; i < 4; ++i) { agp[i] = agp0[i]; bgp[i] = bgp0[i]; }
    f32x4 ar[4][2];
#pragma unroll
    for (int i = 0; i < 4; ++i) {
      ar[i][0] = *(const f32x4*)(agp[i]);
      ar[i][1] = *(const f32x4*)(agp[i] + 4);
      agp[i] += BK;
    }
#pragma unroll
    for (int i = 0; i < 4; ++i) {
      load16_g2l(bgp[i], &Bs[0][(size_t)(i * 256 + tid) * 8]);
      bgp[i] += BK;
    }
    for (int kt = 0; kt < 4; ++kt) {
      __syncthreads();
#pragma unroll
      for (int i = 0; i < 4; ++i) {
        bf16x8 w;
#pragma unroll
        for (int j = 0; j < 4; ++j) { w[j] = f2bf(ar[i][0][j]); w[4 + j] = f2bf(ar[i][1][j]); }
        ((bf16x8*)As)[aslot[i]] = w;
      }
      __syncthreads();
      if (kt < 3) {
#pragma unroll
        for (int i = 0; i < 4; ++i) {
          ar[i][0] = *(const f32x4*)(agp[i]);
          ar[i][1] = *(const f32x4*)(agp[i] + 4);
          agp[i] += BK;
        }
#pragma unroll
        for (int i = 0; i < 4; ++i) {
          load16_g2l(bgp[i], &Bs[(kt + 1) & 1][(size_t)(i * 256 + tid) * 8]);
          bgp[i] += BK;
        }
      }
      // no compute phase
    }
  }
  // keep LDS contents observable (no DCE)
  dummy[(size_t)blockIdx.x * 256 + tid] = (float)As[tid] + (float)Bs[0][tid] + (float)Bs[1][tid];
}

// ---------------- DIAG 2: staging + ds_read + MFMA, REP x (no tanh/shuffle/atomic) ----------------
__global__ __launch_bounds__(256, 3) void k_diag_smfma(
    const float* __restrict__ F, const short* __restrict__ W1T, float* __restrict__ dummy) {
  __shared__ __align__(16) short As[BM * BK];
  __shared__ __align__(16) short Bs[2][BN * BK];
  const int tid = threadIdx.x;
  const int lane = tid & 63;
  const int hi = lane >> 4;
  const int wid = tid >> 6;
  const int wr = wid >> 1, wc = wid & 1;
  const int tile = ((blockIdx.x & 7) << 10) | (blockIdx.x >> 3);
  const int ntile = tile & 3;
  const int mtile = tile >> 2;
  const int m0 = mtile * BM;
  const int n0 = ntile * BN;

  const bf16x8* As8 = (const bf16x8*)As;

  const float* agp0[4];
  int aslot[4];
  const short* bgp0[4];
#pragma unroll
  for (int i = 0; i < 4; ++i) {
    int s = i * 256 + tid;
    int arow = s >> 3;
    int akq = (s & 7) ^ (arow & 7);
    agp0[i] = F + (size_t)(m0 + arow) * D_ + akq * 8;
    aslot[i] = s;
    bgp0[i] = W1T + (size_t)(n0 + arow) * D_ + akq * 8;
  }

  f32x4 acc[4][4];
  const f32x4 fz = {0.f, 0.f, 0.f, 0.f};
#pragma unroll
  for (int mi = 0; mi < 4; ++mi)
#pragma unroll
    for (int ni = 0; ni < 4; ++ni) acc[mi][ni] = fz;

  for (int rep = 0; rep < REP; ++rep) {
    const float* agp[4];
    const short* bgp[4];
#pragma unroll
    for (int i = 0; i < 4; ++i) { agp[i] = agp0[i]; bgp[i] = bgp0[i]; }
    f32x4 ar[4][2];
#pragma unroll
    for (int i = 0; i < 4; ++i) {
      ar[i][0] = *(const f32x4*)(agp[i]);
      ar[i][1] = *(const f32x4*)(agp[i] + 4);
      agp[i] += BK;
    }
#pragma unroll
    for (int i = 0; i < 4; ++i) {
      load16_g2l(bgp[i], &Bs[0][(size_t)(i * 256 + tid) * 8]);
      bgp[i] += BK;
    }
    for (int kt = 0; kt < 4; ++kt) {
      const bf16x8* BsC = (const bf16x8*)Bs[kt & 1];
      __syncthreads();
#pragma unroll
      for (int i = 0; i < 4; ++i) {
        bf16x8 w;
#pragma unroll
        for (int j = 0; j < 4; ++j) { w[j] = f2bf(ar[i][0][j]); w[4 + j] = f2bf(ar[i][1][j]); }
        ((bf16x8*)As)[aslot[i]] = w;
      }
      __syncthreads();
      if (kt < 3) {
#pragma unroll
        for (int i = 0; i < 4; ++i) {
          ar[i][0] = *(const f32x4*)(agp[i]);
          ar[i][1] = *(const f32x4*)(agp[i] + 4);
          agp[i] += BK;
        }
#pragma unroll
        for (int i = 0; i < 4; ++i) {
          load16_g2l(bgp[i], &Bs[(kt + 1) & 1][(size_t)(i * 256 + tid) * 8]);
          bgp[i] += BK;
        }
      }
#pragma unroll
      for (int kk = 0; kk < 2; ++kk) {
        bf16x8 af[4], bfr[4];
#pragma unroll
        for (int mi = 0; mi < 4; ++mi) {
          int rA = wr * 64 + mi * 16 + (lane & 15);
          af[mi] = As8[rA * 8 + ((kk * 4 + hi) ^ (rA & 7))];
        }
#pragma unroll
        for (int ni = 0; ni < 4; ++ni) {
          int nB = wc * 64 + ni * 16 + (lane & 15);
          bfr[ni] = BsC[nB * 8 + ((kk * 4 + hi) ^ (nB & 7))];
        }
#pragma unroll
        for (int mi = 0; mi < 4; ++mi)
#pragma unroll
          for (int ni = 0; ni < 4; ++ni)
            acc[mi][ni] = __builtin_amdgcn_mfma_f32_16x16x32_bf16(af[mi], bfr[ni], acc[mi][ni], 0, 0, 0);
      }
    }
  }
  float s = 0.f;
#pragma unroll
  for (int mi = 0; mi < 4; ++mi)
#pragma unroll
    for (int ni = 0; ni < 4; ++ni)
      s += acc[mi][ni][0] + acc[mi][ni][1] + acc[mi][ni][2] + acc[mi][ni][3];
  dummy[(size_t)blockIdx.x * 256 + tid] = s;
}

// ---------------- fused: softmax + context ----------------
__global__ void k_smctx(const float* __restrict__ logits, const float* __restrict__ F,
                        float* __restrict__ outw, float* __restrict__ ctx) {
  __shared__ float wl[L_];
  __shared__ f32x4 part[256];
  __shared__ float red[8];
  int b = blockIdx.x, t = threadIdx.x;
  float x = logits[(size_t)b * L_ + t];
  float m = x;
#pragma unroll
  for (int off = 32; off >= 1; off >>= 1) m = fmaxf(m, __shfl_xor(m, off));
  if ((t & 63) == 0) red[t >> 6] = m;
  __syncthreads();
  m = fmaxf(fmaxf(red[0], red[1]), fmaxf(red[2], red[3]));
  float e = __expf(x - m);
  float s = e;
#pragma unroll
  for (int off = 32; off >= 1; off >>= 1) s += __shfl_xor(s, off);
  if ((t & 63) == 0) red[4 + (t >> 6)] = s;
  __syncthreads();
  s = (red[4] + red[5]) + (red[6] + red[7]);
  float w = e / s;
  outw[(size_t)b * L_ + t] = w;
  wl[t] = w;
  __syncthreads();

  int lq = t >> 6, dq = t & 63;
  const f32x4* F4 = (const f32x4*)(F + (size_t)b * L_ * D_);
  f32x4 acc = {0.f, 0.f, 0.f, 0.f};
  for (int l = lq; l < L_; l += 4) acc += wl[l] * F4[l * 64 + dq];
  part[t] = acc;
  __syncthreads();
  if (lq == 0) {
    f32x4 r = (part[t] + part[t + 64]) + (part[t + 128] + part[t + 192]);
    ((f32x4*)ctx)[(size_t)b * 64 + dq] = r;
  }
}

extern "C" void kernel_launch(void* const* d_in, const int* in_sizes, int n_in,
                              void* d_out, int out_size, void* d_ws, size_t ws_size,
                              hipStream_t stream) {
  const float* F      = (const float*)d_in[0];
  const float* hidden = (const float*)d_in[1];
  const float* W1     = (const float*)d_in[2];
  const float* b1     = (const float*)d_in[3];
  const float* W2     = (const float*)d_in[4];
  const float* b2     = (const float*)d_in[5];
  const float* Wv     = (const float*)d_in[6];
  // d_in[7] = bv: shift-invariant under softmax, unused

  float* out_ctx = (float*)d_out;                 // [B,D]
  float* out_w   = out_ctx + (size_t)B_ * D_;     // [B,L]

  char* ws = (char*)d_ws;
  short* W1T    = (short*)ws;                          // 256 KB
  float* ph     = (float*)(ws + 262144);               // 2 MB
  float* logits = (float*)(ws + 262144 + 2097152);     // 1 MB
  float* dummy  = (float*)(ws + 16777216);             // 8 MB diag scratch @16MB

  hipMemsetAsync(logits, 0, (size_t)M_ * sizeof(float), stream);
  k_w1t<<<512, 256, 0, stream>>>(W1, W1T);
  k_projh<<<dim3(2, 128), 256, 0, stream>>>(hidden, W2, b1, b2, ph);
  k_gemm<<<8192, 256, 0, stream>>>(F, W1T, ph, Wv, logits);
  k_smctx<<<1024, 256, 0, stream>>>(logits, F, out_w, out_ctx);

  // ---- ablation diagnostics (write only to dummy scratch; dur_us sacrificial) ----
  if (ws_size >= 16777216 + (size_t)8192 * 256 * sizeof(float)) {
    k_diag_stage<<<8192, 256, 0, stream>>>(F, W1T, dummy);
    k_diag_smfma<<<8192, 256, 0, stream>>>(F, W1T, dummy);
  }
}